// Round 14
// baseline (916.951 us; speedup 1.0000x reference)
//
#include <hip/hip_runtime.h>

// SelectivePSI forward: bf16 MFMA GEMMs + chunked parallel scans.
// B=4, S=4096, D=1024, R=128. fp32 in/out, bf16 internals.
// Half-split (B=2 per pass). dt low-rank folded into mega-GEMM via Wcomb=Wdd@Wdu.
// MEGA GEMM: faithful 8-phase 256x256xBK64 template (8 waves, 128KB LDS dbuf,
// quadrant phases, reg-cached A/B halves, counted vmcnt(8), XOR swizzle).
// Other GEMMs: proven R8 gemmH (2-buf, vmcnt(4), 2 barriers).

#define D_ 1024
#define S_ 4096
#define MH 8192              // tokens per half (B=2)
#define CHUNK 64

typedef float f32x4 __attribute__((ext_vector_type(4)));
typedef __bf16 bf16x8 __attribute__((ext_vector_type(8)));
typedef short s16x8 __attribute__((ext_vector_type(8)));

typedef __attribute__((address_space(1))) void gvoid;
typedef __attribute__((address_space(3))) void lvoid;

__device__ __forceinline__ void g2l16(const void* g, void* l) {
  __builtin_amdgcn_global_load_lds((gvoid*)g, (lvoid*)l, 16, 0, 0);
}

__device__ __forceinline__ float bflo(unsigned int w){ union{unsigned int i; float f;} c; c.i = w<<16; return c.f; }
__device__ __forceinline__ float bfhi(unsigned int w){ union{unsigned int i; float f;} c; c.i = w & 0xFFFF0000u; return c.f; }
__device__ __forceinline__ unsigned short f2bf(float f){
  union{float f; unsigned int i;} c; c.f=f;
  unsigned int u = c.i + 0x7FFFu + ((c.i>>16)&1u);
  return (unsigned short)(u>>16);
}
__device__ __forceinline__ unsigned int pack2(float lo, float hi){
  return (unsigned int)f2bf(lo) | ((unsigned int)f2bf(hi)<<16);
}

__device__ __forceinline__ float sig_(float x){ return 1.f/(1.f+__expf(-x)); }
__device__ __forceinline__ float gelu_(float x){ return 0.5f*x*(1.f+erff(x*0.70710678118654752440f)); }
__device__ __forceinline__ float softplus_(float x){ return (x>0.f) ? x + log1pf(__expf(-x)) : log1pf(__expf(x)); }

// ================= 8-phase 256x256 mega GEMM (K=1024, BK=64) =================
// C[MH,6144] = A[MH,1024] @ Bt[6144,1024]^T, fused per-slice epilogues.
// 512 thr = 8 waves (2m x 4n); per-wave out 128x64 = acc[8][4].
// LDS: As/Bs [2][256][64] bf16 = 128 KiB. 16 K-tiles, 2 per iteration.
// Swizzle: LDS row r chunk c (16B) holds global chunk c ^ (r&7); read applies
// the same XOR (both-sides involution; R6/R10-verified family).

#define LDA8(buf, MHH, dst) do { \
  _Pragma("unroll") for (int f_=0; f_<4; f_++) \
  _Pragma("unroll") for (int ks_=0; ks_<2; ks_++) \
    dst[f_][ks_] = *(const s16x8*)&As[buf][(size_t)(wm*128 + (MHH)*64 + f_*16 + fr)*64 + ((ks_*32 + fg*8) ^ swz)]; \
} while(0)

#define LDB8(buf, NHH, dst) do { \
  _Pragma("unroll") for (int g_=0; g_<2; g_++) \
  _Pragma("unroll") for (int ks_=0; ks_<2; ks_++) \
    dst[g_][ks_] = *(const s16x8*)&Bs[buf][(size_t)(wn*64 + (NHH)*32 + g_*16 + fr)*64 + ((ks_*32 + fg*8) ^ swz)]; \
} while(0)

#define MMQ8(MHH, NHH, a, b) do { \
  __builtin_amdgcn_s_setprio(1); \
  _Pragma("unroll") for (int f_=0; f_<4; f_++) \
  _Pragma("unroll") for (int g_=0; g_<2; g_++) \
  _Pragma("unroll") for (int ks_=0; ks_<2; ks_++) \
    acc[(MHH)*4+f_][(NHH)*2+g_] = __builtin_amdgcn_mfma_f32_16x16x32_bf16( \
      __builtin_bit_cast(bf16x8, a[f_][ks_]), __builtin_bit_cast(bf16x8, b[g_][ks_]), \
      acc[(MHH)*4+f_][(NHH)*2+g_], 0, 0, 0); \
  __builtin_amdgcn_s_setprio(0); \
} while(0)

#define KTILE8(buf) do { \
  s16x8 a0_[4][2], a1_[4][2], b0_[2][2], b1_[2][2]; \
  LDA8(buf, 0, a0_); LDB8(buf, 0, b0_); \
  __builtin_amdgcn_sched_barrier(0); __builtin_amdgcn_s_barrier(); \
  MMQ8(0, 0, a0_, b0_); \
  __builtin_amdgcn_s_barrier(); __builtin_amdgcn_sched_barrier(0); \
  LDB8(buf, 1, b1_); \
  __builtin_amdgcn_sched_barrier(0); __builtin_amdgcn_s_barrier(); \
  MMQ8(0, 1, a0_, b1_); \
  __builtin_amdgcn_s_barrier(); __builtin_amdgcn_sched_barrier(0); \
  LDA8(buf, 1, a1_); \
  __builtin_amdgcn_sched_barrier(0); __builtin_amdgcn_s_barrier(); \
  MMQ8(1, 1, a1_, b1_); \
  __builtin_amdgcn_s_barrier(); __builtin_amdgcn_sched_barrier(0); \
  __builtin_amdgcn_s_barrier(); \
  MMQ8(1, 0, a1_, b0_); \
  __builtin_amdgcn_s_barrier(); __builtin_amdgcn_sched_barrier(0); \
} while(0)

__global__ __launch_bounds__(512)
void gemm8p(const unsigned short* __restrict__ A,
            const unsigned short* __restrict__ Bt,
            const float* __restrict__ bias,
            unsigned short* __restrict__ out0)
{
  __shared__ unsigned short As[2][256*64];   // 64 KB
  __shared__ unsigned short Bs[2][256*64];   // 64 KB
  const int tid = threadIdx.x;
  const int m0 = blockIdx.x * 256;
  const int n0 = blockIdx.y * 256;
  const int lane = tid & 63;
  const int w  = tid >> 6;
  const int wm = w >> 2, wn = w & 3;
  const int fr = lane & 15, fg = lane >> 4;
  const int swz = (fr & 7) << 3;             // read-side chunk XOR (shorts)
  const int KK = 1024;

  // staging: call j covers rows 64j..64j+63; lane row = 64j + (tid>>3),
  // source 16B chunk = (tid&7) ^ (row&7); LDS dest linear (tid*16B + 8KB*j).
  const int srow = tid >> 3;
  const int csrc = ((tid & 7) ^ (srow & 7)) * 8;
  const unsigned short* Ag = A  + (size_t)(m0 + srow)*KK + csrc;
  const unsigned short* Bg = Bt + (size_t)(n0 + srow)*KK + csrc;

  f32x4 acc[8][4];
#pragma unroll
  for (int i=0;i<8;i++)
#pragma unroll
    for (int j=0;j<4;j++)
#pragma unroll
      for (int q=0;q<4;q++) acc[i][j][q] = 0.f;

  auto STAGE = [&](int buf, int t) {         // 8 loads: A x4 + B x4 (8KB each)
    const int k0 = t << 6;
#pragma unroll
    for (int j = 0; j < 4; j++) {
      g2l16(Ag + k0 + (size_t)(64*j)*KK, &As[buf][(size_t)tid*8 + 4096*j]);
      g2l16(Bg + k0 + (size_t)(64*j)*KK, &Bs[buf][(size_t)tid*8 + 4096*j]);
    }
  };

  STAGE(0, 0);
  STAGE(1, 1);
  for (int i = 0; i < 8; ++i) {
    // buf0 (tile 2i) ready: 16 outstanding -> retire oldest 8
    asm volatile("s_waitcnt vmcnt(8)" ::: "memory");
    __builtin_amdgcn_s_barrier();
    __builtin_amdgcn_sched_barrier(0);
    KTILE8(0);
    if (i < 7) STAGE(0, 2*i + 2);            // buf0 free (all waves past barrier)
    if (i < 7) { asm volatile("s_waitcnt vmcnt(8)" ::: "memory"); }
    else       { asm volatile("s_waitcnt vmcnt(0)" ::: "memory"); }
    __builtin_amdgcn_s_barrier();
    __builtin_amdgcn_sched_barrier(0);
    KTILE8(1);
    if (i < 7) STAGE(1, 2*i + 3);
  }

  const int slice = n0 >> 10;                // 256 | 1024 -> uniform per block
#pragma unroll
  for (int mf=0; mf<8; mf++) {
#pragma unroll
    for (int nf=0; nf<4; nf++) {
      const int gn = n0 + wn*64 + nf*16 + fr;
      const float bv = bias[gn];
#pragma unroll
      for (int q=0; q<4; q++) {
        const int gm = m0 + wm*128 + mf*16 + fg*4 + q;
        const float z = acc[mf][nf][q] + bv;
        const float r = (slice==1) ? sig_(z)*5.f
                      : (slice==3) ? sig_(z)
                      : (slice==4) ? softplus_(z)
                      : (slice==5) ? gelu_(z) : z;   // 0 omega, 2 qoff: linear
        out0[(size_t)slice*((size_t)MH*1024) + (size_t)gm*1024 + (gn & 1023)] = f2bf(r);
      }
    }
  }
}

// ---------------- R8 128x128 GEMM (p2 / out1 / out2 / Wcomb) ----------------
// EPI 1: lin+bias -> out0            (p2 -> zpin)
// EPI 2: gelu+bias -> out0           (out1 -> a3)
// EPI 3: lin+bias+extra -> fp32 outf (out2 + residual)
// EPI 4: lin no-bias -> out0         (Wcomb prep, M=N=1024, KK=128)
template<int EPI, int KK>
__global__ __launch_bounds__(256)
void gemmH(const unsigned short* __restrict__ A,
           const unsigned short* __restrict__ Bt,
           const float* __restrict__ bias,
           const float* __restrict__ extra,
           unsigned short* __restrict__ out0,
           float* __restrict__ outf)
{
  __shared__ unsigned short As[2][128*32];
  __shared__ unsigned short Bs[2][128*32];
  const int tid = threadIdx.x;
  const int m0 = blockIdx.x * 128;
  const int n0 = blockIdx.y * 128;
  const int lane = tid & 63;
  const int wv = tid >> 6;
  const int wr = wv >> 1, wc = wv & 1;
  const int fr = lane & 15, fg = lane >> 4;

  const int r0 = tid >> 2;
  const int k8 = (tid & 3) * 8;

  const unsigned short* ArowA = A  + (size_t)(m0+r0)*KK + k8;
  const unsigned short* ArowB = A  + (size_t)(m0+r0+64)*KK + k8;
  const unsigned short* BrowA = Bt + (size_t)(n0+r0)*KK + k8;
  const unsigned short* BrowB = Bt + (size_t)(n0+r0+64)*KK + k8;

  f32x4 acc[4][4];
#pragma unroll
  for (int i=0;i<4;i++)
#pragma unroll
    for (int j=0;j<4;j++)
#pragma unroll
      for (int q=0;q<4;q++) acc[i][j][q] = 0.f;

  auto STAGE = [&](int buf, int t) {
    const int k0 = t << 5;
    g2l16(ArowA + k0, &As[buf][(size_t)tid*8]);
    g2l16(ArowB + k0, &As[buf][(size_t)(tid+256)*8]);
    g2l16(BrowA + k0, &Bs[buf][(size_t)tid*8]);
    g2l16(BrowB + k0, &Bs[buf][(size_t)(tid+256)*8]);
  };
  auto COMPUTE = [&](int buf) {
    s16x8 af[4], bfr[4];
#pragma unroll
    for (int mf=0; mf<4; mf++) af[mf]  = *(const s16x8*)&As[buf][(wr*64 + mf*16 + fr)*32 + fg*8];
#pragma unroll
    for (int nf=0; nf<4; nf++) bfr[nf] = *(const s16x8*)&Bs[buf][(wc*64 + nf*16 + fr)*32 + fg*8];
#pragma unroll
    for (int mf=0; mf<4; mf++)
#pragma unroll
      for (int nf=0; nf<4; nf++)
        acc[mf][nf] = __builtin_amdgcn_mfma_f32_16x16x32_bf16(
          __builtin_bit_cast(bf16x8, af[mf]), __builtin_bit_cast(bf16x8, bfr[nf]),
          acc[mf][nf], 0, 0, 0);
  };

  const int nt = KK >> 5;
  STAGE(0, 0);
  STAGE(1, 1);
  int cur = 0;
  for (int t = 0; t < nt - 1; ++t) {
    asm volatile("s_waitcnt vmcnt(4)" ::: "memory");
    __builtin_amdgcn_s_barrier();
    __builtin_amdgcn_sched_barrier(0);
    COMPUTE(cur);
    __builtin_amdgcn_s_barrier();
    __builtin_amdgcn_sched_barrier(0);
    if (t + 2 < nt) STAGE(cur, t + 2);
    cur ^= 1;
  }
  asm volatile("s_waitcnt vmcnt(0)" ::: "memory");
  __builtin_amdgcn_s_barrier();
  __builtin_amdgcn_sched_barrier(0);
  COMPUTE(cur);

#pragma unroll
  for (int mf=0; mf<4; mf++) {
#pragma unroll
    for (int nf=0; nf<4; nf++) {
      const int gn = n0 + wc*64 + nf*16 + fr;
      float bv = 0.f;
      if constexpr (EPI != 4) bv = bias[gn];
#pragma unroll
      for (int q=0; q<4; q++) {
        const int gm = m0 + wr*64 + mf*16 + fg*4 + q;
        const float z = acc[mf][nf][q] + bv;
        if constexpr (EPI == 1) {
          out0[(size_t)gm*1024 + gn] = f2bf(z);
        } else if constexpr (EPI == 2) {
          out0[(size_t)gm*1024 + gn] = f2bf(gelu_(z));
        } else if constexpr (EPI == 3) {
          const size_t idx = (size_t)gm*1024 + gn;
          outf[idx] = z + extra[idx];
        } else {
          out0[(size_t)gm*1024 + gn] = f2bf(z);        // Wcomb
        }
      }
    }
  }
}

// ---------------- prep kernels ----------------
__global__ __launch_bounds__(256)
void cvtx_k(const float* __restrict__ x, unsigned int* __restrict__ hb)
{
  const size_t i = (size_t)blockIdx.x*256 + threadIdx.x;
  const float4 v = *(const float4*)(x + i*4);
  hb[i*2]   = pack2(v.x, v.y);
  hb[i*2+1] = pack2(v.z, v.w);
}

__global__ __launch_bounds__(256)
void tconv_k(const float* __restrict__ W, unsigned short* __restrict__ Wt, int K, int N)
{
  __shared__ float tile[32][33];
  const int kb = blockIdx.x*32, nb = blockIdx.y*32;
  const int tx = threadIdx.x & 31, ty = threadIdx.x >> 5;
#pragma unroll
  for (int i=0;i<32;i+=8) tile[ty+i][tx] = W[(size_t)(kb+ty+i)*N + (nb+tx)];
  __syncthreads();
#pragma unroll
  for (int i=0;i<32;i+=8) Wt[(size_t)(nb+ty+i)*K + (kb+tx)] = f2bf(tile[tx][ty+i]);
}

struct P7 { const float* s[7]; unsigned short* d[7]; };
__global__ __launch_bounds__(256)
void tconv7_k(P7 p)
{
  __shared__ float tile[32][33];
  const float* W = p.s[blockIdx.z];
  unsigned short* Wt = p.d[blockIdx.z];
  const int kb = blockIdx.x*32, nb = blockIdx.y*32;
  const int tx = threadIdx.x & 31, ty = threadIdx.x >> 5;
#pragma unroll
  for (int i=0;i<32;i+=8) tile[ty+i][tx] = W[(size_t)(kb+ty+i)*1024 + (nb+tx)];
  __syncthreads();
#pragma unroll
  for (int i=0;i<32;i+=8) Wt[(size_t)(nb+ty+i)*1024 + (kb+tx)] = f2bf(tile[tx][ty+i]);
}

__global__ __launch_bounds__(256)
void biascat_k(const float* bo, const float* ob, const float* bm, const float* bq,
               const float* bg, const float* bdu, const float* bp1, float* bc)
{
  const int i = blockIdx.x*256 + threadIdx.x;
  if (i >= 6144) return;
  const int s = i >> 10, d = i & 1023;
  float v;
  if (s==0) v = bo[d] + ob[d];
  else if (s==1) v = bm[d];
  else if (s==2) v = bq[d];
  else if (s==3) v = bg[d];
  else if (s==4) v = bdu[d];
  else v = bp1[d];
  bc[i] = v;
}

// ---------------- scans (half = 2 sequences, 128 chunk-rows of 64 steps) ----------------
__global__ __launch_bounds__(256)
void scan1_k(unsigned int* __restrict__ zgate, unsigned int* __restrict__ zmag,
             unsigned int* __restrict__ zomega, const unsigned int* __restrict__ zdt,
             const unsigned int* __restrict__ hb,
             float* __restrict__ sumPhi, float* __restrict__ sumGm)
{
  const int flat = blockIdx.x*256 + threadIdx.x;
  const int dh = flat & 511;
  const int bc = flat >> 9;
  size_t i = (size_t)bc*CHUNK*(D_/2) + dh;
  float sp0=0,sp1=0,sg0=0,sg1=0;
  for (int s=0;s<CHUNK;s++,i+=D_/2) {
    const unsigned ga=zgate[i], mg=zmag[i], om=zomega[i], dt=zdt[i], hh=hb[i];
    const float ga0=bflo(ga), ga1=bfhi(ga), mg0=bflo(mg), mg1=bfhi(mg);
    const float od0 = bflo(om)*bflo(dt)*0.01f, od1 = bfhi(om)*bfhi(dt)*0.01f;
    const unsigned odp = pack2(od0, od1);
    zomega[i] = odp;
    sp0 += bflo(odp); sp1 += bfhi(odp);
    const float g0 = ga0*mg0, g1 = ga1*mg1;
    const unsigned gmp = pack2(g0, g1);
    zmag[i] = gmp;
    sg0 += bflo(gmp); sg1 += bfhi(gmp);
    zgate[i] = pack2(g0*bflo(hh), g1*bfhi(hh));    // content
  }
  const int sidx = bc*D_ + dh*2;
  sumPhi[sidx]=sp0; sumPhi[sidx+1]=sp1;
  sumGm[sidx]=sg0;  sumGm[sidx+1]=sg1;
}

__global__ __launch_bounds__(256)
void scan2_k(float* __restrict__ a, float* __restrict__ b)
{
  const int chain = (blockIdx.x*256 + threadIdx.x) >> 6;  // [0, 2048): b*1024 + d
  const int lane  = threadIdx.x & 63;
  const int bb = chain >> 10, d = chain & 1023;
  const size_t i = (size_t)(bb*64 + lane)*D_ + d;
  const float v = a[i], w = b[i];
  float vi = v, wi = w;
#pragma unroll
  for (int off=1; off<64; off<<=1) {
    const float t = __shfl_up(vi, off, 64);
    const float u = __shfl_up(wi, off, 64);
    if (lane >= off) { vi += t; wi += u; }
  }
  a[i] = vi - v;
  b[i] = wi - w;
}

__global__ __launch_bounds__(256)
void scan3_k(const unsigned int* __restrict__ omdt, const unsigned int* __restrict__ content,
             const unsigned int* __restrict__ phinit, const float* __restrict__ phiOff,
             float* __restrict__ sumRe, float* __restrict__ sumIm)
{
  const int flat = blockIdx.x*256 + threadIdx.x;
  const int dh = flat & 511;
  const int bc = flat >> 9;
  size_t i = (size_t)bc*CHUNK*(D_/2) + dh;
  const int sidx = bc*D_ + dh*2;
  float p0 = phiOff[sidx], p1 = phiOff[sidx+1];
  float re0=0,re1=0,im0=0,im1=0;
  for (int s=0;s<CHUNK;s++,i+=D_/2) {
    const unsigned od = omdt[i], ct = content[i], pi = phinit[i];
    p0 += bflo(od); p1 += bfhi(od);
    const float phi0 = bflo(pi)+p0, phi1 = bfhi(pi)+p1;
    float s0,c0,s1,c1;
    __sincosf(phi0,&s0,&c0);
    __sincosf(phi1,&s1,&c1);
    const float ct0=bflo(ct), ct1=bfhi(ct);
    re0 += ct0*c0; im0 += ct0*s0;
    re1 += ct1*c1; im1 += ct1*s1;
  }
  sumRe[sidx]=re0; sumRe[sidx+1]=re1;
  sumIm[sidx]=im0; sumIm[sidx+1]=im1;
}

__global__ __launch_bounds__(256)
void scan5_k(const unsigned int* __restrict__ omdt, const unsigned int* __restrict__ content,
             const unsigned int* __restrict__ phinit, const unsigned int* __restrict__ gm,
             const unsigned int* __restrict__ qoff,
             const float* __restrict__ phiOff, const float* __restrict__ gmOff,
             const float* __restrict__ reOff, const float* __restrict__ imOff,
             unsigned int* __restrict__ ctx)
{
  const int flat = blockIdx.x*256 + threadIdx.x;
  const int dh = flat & 511;
  const int bc = flat >> 9;
  size_t i = (size_t)bc*CHUNK*(D_/2) + dh;
  const int sidx = bc*D_ + dh*2;
  float p0 = phiOff[sidx], p1 = phiOff[sidx+1];
  float ag0 = gmOff[sidx], ag1 = gmOff[sidx+1];
  float re0 = reOff[sidx], re1 = reOff[sidx+1];
  float im0 = imOff[sidx], im1 = imOff[sidx+1];
  const int mtok0 = bc*CHUNK;
  for (int s=0;s<CHUNK;s++,i+=D_/2) {
    const unsigned od = omdt[i], ct = content[i], pi = phinit[i], gq = gm[i], qo = qoff[i];
    p0 += bflo(od); p1 += bfhi(od);
    const float phi0 = bflo(pi)+p0, phi1 = bfhi(pi)+p1;
    float sn0,cs0,sn1,cs1;
    __sincosf(phi0,&sn0,&cs0);
    __sincosf(phi1,&sn1,&cs1);
    const float ct0=bflo(ct), ct1=bfhi(ct);
    re0 += ct0*cs0; im0 += ct0*sn0;
    re1 += ct1*cs1; im1 += ct1*sn1;
    ag0 += bflo(gq); ag1 += bfhi(gq);
    const float inv0 = rsqrtf(ag0 + 1e-8f), inv1 = rsqrtf(ag1 + 1e-8f);
    const float mr0 = re0*inv0, mi0 = im0*inv0;
    const float mr1 = re1*inv1, mi1 = im1*inv1;
    const float pq0 = phi0 + bflo(qo), pq1 = phi1 + bfhi(qo);
    float sq0,cq0,sq1,cq1;
    __sincosf(pq0,&sq0,&cq0);
    __sincosf(pq1,&sq1,&cq1);
    const size_t cb = (size_t)(mtok0+s)*D_ + dh;
    ctx[cb]        = pack2(mr0*cq0 + mi0*sq0, mr1*cq1 + mi1*sq1);
    ctx[cb + D_/2] = pack2(mi0*cq0 - mr0*sq0, mi1*cq1 - mr1*sq1);
  }
}

// LayerNorm over 2048, in place on bf16 ctx; one block per token
__global__ __launch_bounds__(256)
void ln_k(unsigned int* __restrict__ ctx, const float* __restrict__ gam, const float* __restrict__ bet)
{
  const int m = blockIdx.x, tid = threadIdx.x;
  const size_t base = (size_t)m*1024 + tid*4;
  const uint4 t = *(const uint4*)(ctx + base);
  float v[8] = { bflo(t.x), bfhi(t.x), bflo(t.y), bfhi(t.y),
                 bflo(t.z), bfhi(t.z), bflo(t.w), bfhi(t.w) };
  float s=0.f, ss=0.f;
#pragma unroll
  for (int j=0;j<8;j++){ s+=v[j]; ss+=v[j]*v[j]; }
  for (int o=32;o;o>>=1){ s += __shfl_xor(s,o); ss += __shfl_xor(ss,o); }
  __shared__ float red[8];
  const int wv = tid>>6, lane = tid&63;
  if (lane==0){ red[wv]=s; red[4+wv]=ss; }
  __syncthreads();
  s  = red[0]+red[1]+red[2]+red[3];
  ss = red[4]+red[5]+red[6]+red[7];
  const float mu = s*(1.f/2048.f);
  const float rstd = rsqrtf(ss*(1.f/2048.f) - mu*mu + 1e-5f);
  const int col = tid*8;
  float o[8];
#pragma unroll
  for (int j=0;j<8;j++) o[j] = (v[j]-mu)*rstd*gam[col+j] + bet[col+j];
  uint4 w;
  w.x = pack2(o[0],o[1]); w.y = pack2(o[2],o[3]);
  w.z = pack2(o[4],o[5]); w.w = pack2(o[6],o[7]);
  *(uint4*)(ctx + base) = w;
}

extern "C" void kernel_launch(void* const* d_in, const int* in_sizes, int n_in,
                              void* d_out, int out_size, void* d_ws, size_t ws_size,
                              hipStream_t stream)
{
  const float* x     = (const float*)d_in[0];
  const float* Wdd   = (const float*)d_in[1];
  const float* Wdu   = (const float*)d_in[2];
  const float* bdu   = (const float*)d_in[3];
  const float* Wg    = (const float*)d_in[4];
  const float* bg    = (const float*)d_in[5];
  const float* Wp1   = (const float*)d_in[6];
  const float* bp1   = (const float*)d_in[7];
  const float* Wp2   = (const float*)d_in[8];
  const float* bp2   = (const float*)d_in[9];
  const float* obase = (const float*)d_in[10];
  const float* Wo    = (const float*)d_in[11];
  const float* bo    = (const float*)d_in[12];
  const float* Wm    = (const float*)d_in[13];
  const float* bm    = (const float*)d_in[14];
  const float* Wq    = (const float*)d_in[15];
  const float* bq    = (const float*)d_in[16];
  const float* lng   = (const float*)d_in[17];
  const float* lnb   = (const float*)d_in[18];
  const float* Wo1   = (const float*)d_in[19];
  const float* bo1   = (const float*)d_in[20];
  const float* Wo2   = (const float*)d_in[21];
  const float* bo2   = (const float*)d_in[22];

  char* basep = (char*)d_ws;
  size_t off = 0;
  auto alloc = [&](size_t n) { char* q = basep + off; off = (off + n + 255) & ~(size_t)255; return q; };

  const size_t S = (size_t)MH*1024;
  unsigned short* cat1 = (unsigned short*)alloc(7*S*2);                     // 117.4 MB
  unsigned short* zomega = cat1 + 0*S;
  unsigned short* zmag   = cat1 + 1*S;
  unsigned short* zqoff  = cat1 + 2*S;
  unsigned short* zgate  = cat1 + 3*S;
  unsigned short* zdt    = cat1 + 4*S;
  unsigned short* zphi1  = cat1 + 5*S;
  unsigned short* hb     = cat1 + 6*S;
  unsigned short* ctx    = zphi1;        // [MH][2048] aliases phi1+hb (both dead)
  unsigned short* a3     = cat1;         // [MH][1024] aliases omega (dead after scan5)
  unsigned short* zpin   = (unsigned short*)alloc(S*2);
  unsigned short* wt_cat = (unsigned short*)alloc((size_t)6144*1024*2);
  unsigned short* wt_p2  = (unsigned short*)alloc(1024*1024*2);
  unsigned short* wt_du  = (unsigned short*)alloc(1024*128*2);
  unsigned short* wddb   = (unsigned short*)alloc(1024*128*2);
  unsigned short* wt_o1  = (unsigned short*)alloc((size_t)1024*2048*2);
  unsigned short* wt_o2  = (unsigned short*)alloc(1024*1024*2);
  float* bias_cat = (float*)alloc(6144*4);
  float* sumPhi = (float*)alloc((size_t)128*D_*4);
  float* sumGm  = (float*)alloc((size_t)128*D_*4);
  float* sumRe  = (float*)alloc((size_t)128*D_*4);
  float* sumIm  = (float*)alloc((size_t)128*D_*4);
  // total ~158 MB (proven footprint)

  const dim3 blk(256);

  // ---- weight prep ----
  P7 p7;
  p7.s[0]=Wo;  p7.d[0]=wt_cat + (size_t)0*1024*1024;   // slice 0 omega
  p7.s[1]=Wm;  p7.d[1]=wt_cat + (size_t)1*1024*1024;   // slice 1 mag
  p7.s[2]=Wq;  p7.d[2]=wt_cat + (size_t)2*1024*1024;   // slice 2 qoff
  p7.s[3]=Wg;  p7.d[3]=wt_cat + (size_t)3*1024*1024;   // slice 3 gate
  p7.s[4]=Wp1; p7.d[4]=wt_cat + (size_t)5*1024*1024;   // slice 5 phi1
  p7.s[5]=Wp2; p7.d[5]=wt_p2;
  p7.s[6]=Wo2; p7.d[6]=wt_o2;
  tconv7_k<<<dim3(32,32,7), blk, 0, stream>>>(p7);
  tconv_k<<<dim3(4,32),  blk, 0, stream>>>(Wdu, wt_du, 128,1024);
  tconv_k<<<dim3(64,32), blk, 0, stream>>>(Wo1, wt_o1, 2048,1024);
  cvtx_k<<<128, blk, 0, stream>>>(Wdd, (unsigned int*)wddb);
  // Wcomb^T[d][k] = (Wdd@Wdu)[k][d]: C = wt_du @ wddb^T (M=N=1024, K=128) -> slice 4
  gemmH<4,128><<<dim3(8,8), blk, 0, stream>>>(wt_du, wddb, nullptr, nullptr,
                                              wt_cat + (size_t)4*1024*1024, nullptr);
  biascat_k<<<24, blk, 0, stream>>>(bo, obase, bm, bq, bg, bdu, bp1, bias_cat);

  for (int h = 0; h < 2; h++) {
    const float* xh = x + (size_t)h*MH*D_;
    float* outh     = (float*)d_out + (size_t)h*MH*D_;

    cvtx_k<<<MH*D_/1024, blk, 0, stream>>>(xh, (unsigned int*)hb);

    // mega: all 6 projections (N=6144) via 8-phase 256^2 kernel, grid 32x24
    gemm8p<<<dim3(MH/256, 24), dim3(512), 0, stream>>>(hb, wt_cat, bias_cat, cat1);
    // p2: phi_init (from gelu(phi1))
    gemmH<1,1024><<<dim3(MH/128, 8), blk, 0, stream>>>(zphi1, wt_p2, bp2,
                                                       nullptr, zpin, nullptr);
    // scans
    scan1_k<<<256, blk, 0, stream>>>((unsigned int*)zgate,(unsigned int*)zmag,(unsigned int*)zomega,
                                     (const unsigned int*)zdt,(const unsigned int*)hb, sumPhi, sumGm);
    scan2_k<<<512, blk, 0, stream>>>(sumPhi, sumGm);
    scan3_k<<<256, blk, 0, stream>>>((const unsigned int*)zomega,(const unsigned int*)zgate,
                                     (const unsigned int*)zpin, sumPhi, sumRe, sumIm);
    scan2_k<<<512, blk, 0, stream>>>(sumRe, sumIm);
    scan5_k<<<256, blk, 0, stream>>>((const unsigned int*)zomega,(const unsigned int*)zgate,
                                     (const unsigned int*)zpin,(const unsigned int*)zmag,
                                     (const unsigned int*)zqoff,
                                     sumPhi, sumGm, sumRe, sumIm, (unsigned int*)ctx);

    // tail: LN + out MLP + residual
    ln_k<<<MH, blk, 0, stream>>>((unsigned int*)ctx, lng, lnb);
    gemmH<2,2048><<<dim3(MH/128, 8), blk, 0, stream>>>(ctx, wt_o1, bo1,
                                                       nullptr, a3, nullptr);
    gemmH<3,1024><<<dim3(MH/128, 8), blk, 0, stream>>>(a3, wt_o2, bo2,
                                                       xh, nullptr, outh);
  }
}

// Round 15
// 827.078 us; speedup vs baseline: 1.1087x; 1.1087x over previous
//
#include <hip/hip_runtime.h>

// SelectivePSI forward: bf16 MFMA GEMMs + chunked parallel scans.
// B=4, S=4096, D=1024, R=128. fp32 in/out, bf16 internals.
// Half-split (B=2 per pass). dt low-rank folded into mega-GEMM via Wcomb=Wdd@Wdu.
// FINAL: R8/R13 best configuration (829.8 us, reproduced): 2-buf LDS, counted
// vmcnt(4), raw barriers, m-major grid, no swizzle, no setprio, no XCD remap.
// Ledger: every structural variant regressed or was null (R4 983, R6 931,
// R7 1347, R9 952, R10 840(swz null), R11 907, R12 882, R14 917(8-phase port)).

#define D_ 1024
#define S_ 4096
#define MH 8192              // tokens per half (B=2)
#define CHUNK 64

typedef float f32x4 __attribute__((ext_vector_type(4)));
typedef __bf16 bf16x8 __attribute__((ext_vector_type(8)));
typedef short s16x8 __attribute__((ext_vector_type(8)));

typedef __attribute__((address_space(1))) void gvoid;
typedef __attribute__((address_space(3))) void lvoid;

__device__ __forceinline__ void g2l16(const void* g, void* l) {
  __builtin_amdgcn_global_load_lds((gvoid*)g, (lvoid*)l, 16, 0, 0);
}

__device__ __forceinline__ float bflo(unsigned int w){ union{unsigned int i; float f;} c; c.i = w<<16; return c.f; }
__device__ __forceinline__ float bfhi(unsigned int w){ union{unsigned int i; float f;} c; c.i = w & 0xFFFF0000u; return c.f; }
__device__ __forceinline__ unsigned short f2bf(float f){
  union{float f; unsigned int i;} c; c.f=f;
  unsigned int u = c.i + 0x7FFFu + ((c.i>>16)&1u);
  return (unsigned short)(u>>16);
}
__device__ __forceinline__ unsigned int pack2(float lo, float hi){
  return (unsigned int)f2bf(lo) | ((unsigned int)f2bf(hi)<<16);
}

__device__ __forceinline__ float sig_(float x){ return 1.f/(1.f+__expf(-x)); }
__device__ __forceinline__ float gelu_(float x){ return 0.5f*x*(1.f+erff(x*0.70710678118654752440f)); }
__device__ __forceinline__ float softplus_(float x){ return (x>0.f) ? x + log1pf(__expf(-x)) : log1pf(__expf(x)); }

// ---------------- GEMM: C[M,N] = A[M,KK] @ Bt[N,KK]^T, 128x128 tile, BK=32 ----------------
// EPI 0: mega (N=6144): slice n0>>10: 0 omega->lin(+base in bias), 1 mag->sig*5,
//        2 qoff->lin, 3 gate->sig, 4 dt->softplus, 5 phi1->gelu; out0[slice][MH][1024].
// EPI 1: lin+bias -> out0            (p2 -> zpin)
// EPI 2: gelu+bias -> out0           (out1 -> a3)
// EPI 3: lin+bias+extra -> fp32 outf (out2 + residual)
// EPI 4: lin no-bias -> out0         (Wcomb prep, M=N=1024, KK=128)
template<int EPI, int KK>
__global__ __launch_bounds__(256)
void gemmH(const unsigned short* __restrict__ A,
           const unsigned short* __restrict__ Bt,
           const float* __restrict__ bias,
           const float* __restrict__ extra,
           unsigned short* __restrict__ out0,
           float* __restrict__ outf)
{
  __shared__ unsigned short As[2][128*32];
  __shared__ unsigned short Bs[2][128*32];
  const int tid = threadIdx.x;
  const int m0 = blockIdx.x * 128;
  const int n0 = blockIdx.y * 128;
  const int lane = tid & 63;
  const int wv = tid >> 6;
  const int wr = wv >> 1, wc = wv & 1;
  const int fr = lane & 15, fg = lane >> 4;

  const int r0 = tid >> 2;
  const int k8 = (tid & 3) * 8;

  const unsigned short* ArowA = A  + (size_t)(m0+r0)*KK + k8;
  const unsigned short* ArowB = A  + (size_t)(m0+r0+64)*KK + k8;
  const unsigned short* BrowA = Bt + (size_t)(n0+r0)*KK + k8;
  const unsigned short* BrowB = Bt + (size_t)(n0+r0+64)*KK + k8;

  f32x4 acc[4][4];
#pragma unroll
  for (int i=0;i<4;i++)
#pragma unroll
    for (int j=0;j<4;j++)
#pragma unroll
      for (int q=0;q<4;q++) acc[i][j][q] = 0.f;

  auto STAGE = [&](int buf, int t) {
    const int k0 = t << 5;
    g2l16(ArowA + k0, &As[buf][(size_t)tid*8]);
    g2l16(ArowB + k0, &As[buf][(size_t)(tid+256)*8]);
    g2l16(BrowA + k0, &Bs[buf][(size_t)tid*8]);
    g2l16(BrowB + k0, &Bs[buf][(size_t)(tid+256)*8]);
  };
  auto COMPUTE = [&](int buf) {
    s16x8 af[4], bfr[4];
#pragma unroll
    for (int mf=0; mf<4; mf++) af[mf]  = *(const s16x8*)&As[buf][(wr*64 + mf*16 + fr)*32 + fg*8];
#pragma unroll
    for (int nf=0; nf<4; nf++) bfr[nf] = *(const s16x8*)&Bs[buf][(wc*64 + nf*16 + fr)*32 + fg*8];
#pragma unroll
    for (int mf=0; mf<4; mf++)
#pragma unroll
      for (int nf=0; nf<4; nf++)
        acc[mf][nf] = __builtin_amdgcn_mfma_f32_16x16x32_bf16(
          __builtin_bit_cast(bf16x8, af[mf]), __builtin_bit_cast(bf16x8, bfr[nf]),
          acc[mf][nf], 0, 0, 0);
  };

  const int nt = KK >> 5;            // >= 4 always
  STAGE(0, 0);
  STAGE(1, 1);
  int cur = 0;
  for (int t = 0; t < nt - 1; ++t) {
    asm volatile("s_waitcnt vmcnt(4)" ::: "memory");   // retire current tile only
    __builtin_amdgcn_s_barrier();
    __builtin_amdgcn_sched_barrier(0);
    COMPUTE(cur);
    __builtin_amdgcn_s_barrier();
    __builtin_amdgcn_sched_barrier(0);
    if (t + 2 < nt) STAGE(cur, t + 2);
    cur ^= 1;
  }
  asm volatile("s_waitcnt vmcnt(0)" ::: "memory");
  __builtin_amdgcn_s_barrier();
  __builtin_amdgcn_sched_barrier(0);
  COMPUTE(cur);

  const int slice = n0 >> 10;
#pragma unroll
  for (int mf=0; mf<4; mf++) {
#pragma unroll
    for (int nf=0; nf<4; nf++) {
      const int gn = n0 + wc*64 + nf*16 + fr;
      float bv = 0.f;
      if constexpr (EPI != 4) bv = bias[gn];
#pragma unroll
      for (int q=0; q<4; q++) {
        const int gm = m0 + wr*64 + mf*16 + fg*4 + q;
        const float z = acc[mf][nf][q] + bv;
        if constexpr (EPI == 0) {
          const float r = (slice==1) ? sig_(z)*5.f
                        : (slice==3) ? sig_(z)
                        : (slice==4) ? softplus_(z)
                        : (slice==5) ? gelu_(z) : z;   // 0 omega, 2 qoff: linear
          out0[(size_t)slice*((size_t)MH*1024) + (size_t)gm*1024 + (gn & 1023)] = f2bf(r);
        } else if constexpr (EPI == 1) {
          out0[(size_t)gm*1024 + gn] = f2bf(z);
        } else if constexpr (EPI == 2) {
          out0[(size_t)gm*1024 + gn] = f2bf(gelu_(z));
        } else if constexpr (EPI == 3) {
          const size_t idx = (size_t)gm*1024 + gn;
          outf[idx] = z + extra[idx];
        } else {
          out0[(size_t)gm*1024 + gn] = f2bf(z);        // Wcomb
        }
      }
    }
  }
}

// ---------------- prep kernels ----------------
__global__ __launch_bounds__(256)
void cvtx_k(const float* __restrict__ x, unsigned int* __restrict__ hb)
{
  const size_t i = (size_t)blockIdx.x*256 + threadIdx.x;
  const float4 v = *(const float4*)(x + i*4);
  hb[i*2]   = pack2(v.x, v.y);
  hb[i*2+1] = pack2(v.z, v.w);
}

__global__ __launch_bounds__(256)
void tconv_k(const float* __restrict__ W, unsigned short* __restrict__ Wt, int K, int N)
{
  __shared__ float tile[32][33];
  const int kb = blockIdx.x*32, nb = blockIdx.y*32;
  const int tx = threadIdx.x & 31, ty = threadIdx.x >> 5;
#pragma unroll
  for (int i=0;i<32;i+=8) tile[ty+i][tx] = W[(size_t)(kb+ty+i)*N + (nb+tx)];
  __syncthreads();
#pragma unroll
  for (int i=0;i<32;i+=8) Wt[(size_t)(nb+ty+i)*K + (kb+tx)] = f2bf(tile[tx][ty+i]);
}

struct P7 { const float* s[7]; unsigned short* d[7]; };
__global__ __launch_bounds__(256)
void tconv7_k(P7 p)   // 7x (1024x1024) transposes batched on grid.z
{
  __shared__ float tile[32][33];
  const float* W = p.s[blockIdx.z];
  unsigned short* Wt = p.d[blockIdx.z];
  const int kb = blockIdx.x*32, nb = blockIdx.y*32;
  const int tx = threadIdx.x & 31, ty = threadIdx.x >> 5;
#pragma unroll
  for (int i=0;i<32;i+=8) tile[ty+i][tx] = W[(size_t)(kb+ty+i)*1024 + (nb+tx)];
  __syncthreads();
#pragma unroll
  for (int i=0;i<32;i+=8) Wt[(size_t)(nb+ty+i)*1024 + (kb+tx)] = f2bf(tile[tx][ty+i]);
}

__global__ __launch_bounds__(256)
void biascat_k(const float* bo, const float* ob, const float* bm, const float* bq,
               const float* bg, const float* bdu, const float* bp1, float* bc)
{
  const int i = blockIdx.x*256 + threadIdx.x;
  if (i >= 6144) return;
  const int s = i >> 10, d = i & 1023;
  float v;
  if (s==0) v = bo[d] + ob[d];
  else if (s==1) v = bm[d];
  else if (s==2) v = bq[d];
  else if (s==3) v = bg[d];
  else if (s==4) v = bdu[d];
  else v = bp1[d];
  bc[i] = v;
}

// ---------------- scans (half = 2 sequences, 128 chunk-rows of 64 steps) ----------------
__global__ __launch_bounds__(256)
void scan1_k(unsigned int* __restrict__ zgate, unsigned int* __restrict__ zmag,
             unsigned int* __restrict__ zomega, const unsigned int* __restrict__ zdt,
             const unsigned int* __restrict__ hb,
             float* __restrict__ sumPhi, float* __restrict__ sumGm)
{
  const int flat = blockIdx.x*256 + threadIdx.x;   // 128*(D/2) = 65536
  const int dh = flat & 511;
  const int bc = flat >> 9;                        // [0,128)
  size_t i = (size_t)bc*CHUNK*(D_/2) + dh;
  float sp0=0,sp1=0,sg0=0,sg1=0;
  for (int s=0;s<CHUNK;s++,i+=D_/2) {
    const unsigned ga=zgate[i], mg=zmag[i], om=zomega[i], dt=zdt[i], hh=hb[i];
    const float ga0=bflo(ga), ga1=bfhi(ga), mg0=bflo(mg), mg1=bfhi(mg);
    const float od0 = bflo(om)*bflo(dt)*0.01f, od1 = bfhi(om)*bfhi(dt)*0.01f;
    const unsigned odp = pack2(od0, od1);
    zomega[i] = odp;
    sp0 += bflo(odp); sp1 += bfhi(odp);
    const float g0 = ga0*mg0, g1 = ga1*mg1;
    const unsigned gmp = pack2(g0, g1);
    zmag[i] = gmp;
    sg0 += bflo(gmp); sg1 += bfhi(gmp);
    zgate[i] = pack2(g0*bflo(hh), g1*bfhi(hh));    // content
  }
  const int sidx = bc*D_ + dh*2;
  sumPhi[sidx]=sp0; sumPhi[sidx+1]=sp1;
  sumGm[sidx]=sg0;  sumGm[sidx+1]=sg1;
}

// wave-parallel exclusive scan over 64 chunks; one wave per (b,d) chain, 2 arrays
__global__ __launch_bounds__(256)
void scan2_k(float* __restrict__ a, float* __restrict__ b)
{
  const int chain = (blockIdx.x*256 + threadIdx.x) >> 6;  // [0, 2048): b*1024 + d
  const int lane  = threadIdx.x & 63;                     // chunk c
  const int bb = chain >> 10, d = chain & 1023;
  const size_t i = (size_t)(bb*64 + lane)*D_ + d;
  const float v = a[i], w = b[i];
  float vi = v, wi = w;
#pragma unroll
  for (int off=1; off<64; off<<=1) {
    const float t = __shfl_up(vi, off, 64);
    const float u = __shfl_up(wi, off, 64);
    if (lane >= off) { vi += t; wi += u; }
  }
  a[i] = vi - v;
  b[i] = wi - w;
}

__global__ __launch_bounds__(256)
void scan3_k(const unsigned int* __restrict__ omdt, const unsigned int* __restrict__ content,
             const unsigned int* __restrict__ phinit, const float* __restrict__ phiOff,
             float* __restrict__ sumRe, float* __restrict__ sumIm)
{
  const int flat = blockIdx.x*256 + threadIdx.x;
  const int dh = flat & 511;
  const int bc = flat >> 9;
  size_t i = (size_t)bc*CHUNK*(D_/2) + dh;
  const int sidx = bc*D_ + dh*2;
  float p0 = phiOff[sidx], p1 = phiOff[sidx+1];
  float re0=0,re1=0,im0=0,im1=0;
  for (int s=0;s<CHUNK;s++,i+=D_/2) {
    const unsigned od = omdt[i], ct = content[i], pi = phinit[i];
    p0 += bflo(od); p1 += bfhi(od);
    const float phi0 = bflo(pi)+p0, phi1 = bfhi(pi)+p1;
    float s0,c0,s1,c1;
    __sincosf(phi0,&s0,&c0);
    __sincosf(phi1,&s1,&c1);
    const float ct0=bflo(ct), ct1=bfhi(ct);
    re0 += ct0*c0; im0 += ct0*s0;
    re1 += ct1*c1; im1 += ct1*s1;
  }
  sumRe[sidx]=re0; sumRe[sidx+1]=re1;
  sumIm[sidx]=im0; sumIm[sidx+1]=im1;
}

__global__ __launch_bounds__(256)
void scan5_k(const unsigned int* __restrict__ omdt, const unsigned int* __restrict__ content,
             const unsigned int* __restrict__ phinit, const unsigned int* __restrict__ gm,
             const unsigned int* __restrict__ qoff,
             const float* __restrict__ phiOff, const float* __restrict__ gmOff,
             const float* __restrict__ reOff, const float* __restrict__ imOff,
             unsigned int* __restrict__ ctx)
{
  const int flat = blockIdx.x*256 + threadIdx.x;
  const int dh = flat & 511;
  const int bc = flat >> 9;
  size_t i = (size_t)bc*CHUNK*(D_/2) + dh;
  const int sidx = bc*D_ + dh*2;
  float p0 = phiOff[sidx], p1 = phiOff[sidx+1];
  float ag0 = gmOff[sidx], ag1 = gmOff[sidx+1];
  float re0 = reOff[sidx], re1 = reOff[sidx+1];
  float im0 = imOff[sidx], im1 = imOff[sidx+1];
  const int mtok0 = bc*CHUNK;
  for (int s=0;s<CHUNK;s++,i+=D_/2) {
    const unsigned od = omdt[i], ct = content[i], pi = phinit[i], gq = gm[i], qo = qoff[i];
    p0 += bflo(od); p1 += bfhi(od);
    const float phi0 = bflo(pi)+p0, phi1 = bfhi(pi)+p1;
    float sn0,cs0,sn1,cs1;
    __sincosf(phi0,&sn0,&cs0);
    __sincosf(phi1,&sn1,&cs1);
    const float ct0=bflo(ct), ct1=bfhi(ct);
    re0 += ct0*cs0; im0 += ct0*sn0;
    re1 += ct1*cs1; im1 += ct1*sn1;
    ag0 += bflo(gq); ag1 += bfhi(gq);
    const float inv0 = rsqrtf(ag0 + 1e-8f), inv1 = rsqrtf(ag1 + 1e-8f);
    const float mr0 = re0*inv0, mi0 = im0*inv0;
    const float mr1 = re1*inv1, mi1 = im1*inv1;
    const float pq0 = phi0 + bflo(qo), pq1 = phi1 + bfhi(qo);
    float sq0,cq0,sq1,cq1;
    __sincosf(pq0,&sq0,&cq0);
    __sincosf(pq1,&sq1,&cq1);
    const size_t cb = (size_t)(mtok0+s)*D_ + dh;   // u32 row = 1024
    ctx[cb]        = pack2(mr0*cq0 + mi0*sq0, mr1*cq1 + mi1*sq1);
    ctx[cb + D_/2] = pack2(mi0*cq0 - mr0*sq0, mi1*cq1 - mr1*sq1);
  }
}

// LayerNorm over 2048, in place on bf16 ctx; one block per token
__global__ __launch_bounds__(256)
void ln_k(unsigned int* __restrict__ ctx, const float* __restrict__ gam, const float* __restrict__ bet)
{
  const int m = blockIdx.x, tid = threadIdx.x;
  const size_t base = (size_t)m*1024 + tid*4;
  const uint4 t = *(const uint4*)(ctx + base);
  float v[8] = { bflo(t.x), bfhi(t.x), bflo(t.y), bfhi(t.y),
                 bflo(t.z), bfhi(t.z), bflo(t.w), bfhi(t.w) };
  float s=0.f, ss=0.f;
#pragma unroll
  for (int j=0;j<8;j++){ s+=v[j]; ss+=v[j]*v[j]; }
  for (int o=32;o;o>>=1){ s += __shfl_xor(s,o); ss += __shfl_xor(ss,o); }
  __shared__ float red[8];
  const int wv = tid>>6, lane = tid&63;
  if (lane==0){ red[wv]=s; red[4+wv]=ss; }
  __syncthreads();
  s  = red[0]+red[1]+red[2]+red[3];
  ss = red[4]+red[5]+red[6]+red[7];
  const float mu = s*(1.f/2048.f);
  const float rstd = rsqrtf(ss*(1.f/2048.f) - mu*mu + 1e-5f);
  const int col = tid*8;
  float o[8];
#pragma unroll
  for (int j=0;j<8;j++) o[j] = (v[j]-mu)*rstd*gam[col+j] + bet[col+j];
  uint4 w;
  w.x = pack2(o[0],o[1]); w.y = pack2(o[2],o[3]);
  w.z = pack2(o[4],o[5]); w.w = pack2(o[6],o[7]);
  *(uint4*)(ctx + base) = w;
}

extern "C" void kernel_launch(void* const* d_in, const int* in_sizes, int n_in,
                              void* d_out, int out_size, void* d_ws, size_t ws_size,
                              hipStream_t stream)
{
  const float* x     = (const float*)d_in[0];
  const float* Wdd   = (const float*)d_in[1];
  const float* Wdu   = (const float*)d_in[2];
  const float* bdu   = (const float*)d_in[3];
  const float* Wg    = (const float*)d_in[4];
  const float* bg    = (const float*)d_in[5];
  const float* Wp1   = (const float*)d_in[6];
  const float* bp1   = (const float*)d_in[7];
  const float* Wp2   = (const float*)d_in[8];
  const float* bp2   = (const float*)d_in[9];
  const float* obase = (const float*)d_in[10];
  const float* Wo    = (const float*)d_in[11];
  const float* bo    = (const float*)d_in[12];
  const float* Wm    = (const float*)d_in[13];
  const float* bm    = (const float*)d_in[14];
  const float* Wq    = (const float*)d_in[15];
  const float* bq    = (const float*)d_in[16];
  const float* lng   = (const float*)d_in[17];
  const float* lnb   = (const float*)d_in[18];
  const float* Wo1   = (const float*)d_in[19];
  const float* bo1   = (const float*)d_in[20];
  const float* Wo2   = (const float*)d_in[21];
  const float* bo2   = (const float*)d_in[22];

  char* basep = (char*)d_ws;
  size_t off = 0;
  auto alloc = [&](size_t n) { char* q = basep + off; off = (off + n + 255) & ~(size_t)255; return q; };

  const size_t S = (size_t)MH*1024;     // elements per [MH][1024] buffer
  // cat1 (6 slices) + hb contiguous: [omega][mag][qoff][gate][dt][phi1][hb]
  unsigned short* cat1 = (unsigned short*)alloc(7*S*2);                     // 117.4 MB
  unsigned short* zomega = cat1 + 0*S;
  unsigned short* zmag   = cat1 + 1*S;
  unsigned short* zqoff  = cat1 + 2*S;
  unsigned short* zgate  = cat1 + 3*S;
  unsigned short* zdt    = cat1 + 4*S;
  unsigned short* zphi1  = cat1 + 5*S;
  unsigned short* hb     = cat1 + 6*S;
  unsigned short* ctx    = zphi1;        // [MH][2048] aliases phi1+hb (both dead)
  unsigned short* a3     = cat1;         // [MH][1024] aliases omega (dead after scan5)
  unsigned short* zpin   = (unsigned short*)alloc(S*2);                     // 16.8 MB
  unsigned short* wt_cat = (unsigned short*)alloc((size_t)6144*1024*2);     // 12.6 MB
  unsigned short* wt_p2  = (unsigned short*)alloc(1024*1024*2);
  unsigned short* wt_du  = (unsigned short*)alloc(1024*128*2);
  unsigned short* wddb   = (unsigned short*)alloc(1024*128*2);
  unsigned short* wt_o1  = (unsigned short*)alloc((size_t)1024*2048*2);
  unsigned short* wt_o2  = (unsigned short*)alloc(1024*1024*2);
  float* bias_cat = (float*)alloc(6144*4);
  float* sumPhi = (float*)alloc((size_t)128*D_*4);
  float* sumGm  = (float*)alloc((size_t)128*D_*4);
  float* sumRe  = (float*)alloc((size_t)128*D_*4);
  float* sumIm  = (float*)alloc((size_t)128*D_*4);
  // total ~158 MB (same proven footprint)

  const dim3 blk(256);

  // ---- weight prep ----
  P7 p7;
  p7.s[0]=Wo;  p7.d[0]=wt_cat + (size_t)0*1024*1024;   // slice 0 omega
  p7.s[1]=Wm;  p7.d[1]=wt_cat + (size_t)1*1024*1024;   // slice 1 mag
  p7.s[2]=Wq;  p7.d[2]=wt_cat + (size_t)2*1024*1024;   // slice 2 qoff
  p7.s[3]=Wg;  p7.d[3]=wt_cat + (size_t)3*1024*1024;   // slice 3 gate
  p7.s[4]=Wp1; p7.d[4]=wt_cat + (size_t)5*1024*1024;   // slice 5 phi1
  p7.s[5]=Wp2; p7.d[5]=wt_p2;
  p7.s[6]=Wo2; p7.d[6]=wt_o2;
  tconv7_k<<<dim3(32,32,7), blk, 0, stream>>>(p7);
  tconv_k<<<dim3(4,32),  blk, 0, stream>>>(Wdu, wt_du, 128,1024);
  tconv_k<<<dim3(64,32), blk, 0, stream>>>(Wo1, wt_o1, 2048,1024);
  cvtx_k<<<128, blk, 0, stream>>>(Wdd, (unsigned int*)wddb);   // Wdd fp32 -> bf16, layout as-is
  // Wcomb^T[d][k] = (Wdd@Wdu)[k][d]: C = wt_du @ wddb^T (M=N=1024, K=128) -> slice 4
  gemmH<4,128><<<dim3(8,8), blk, 0, stream>>>(wt_du, wddb, nullptr, nullptr,
                                              wt_cat + (size_t)4*1024*1024, nullptr);
  biascat_k<<<24, blk, 0, stream>>>(bo, obase, bm, bq, bg, bdu, bp1, bias_cat);

  for (int h = 0; h < 2; h++) {
    const float* xh = x + (size_t)h*MH*D_;
    float* outh     = (float*)d_out + (size_t)h*MH*D_;

    cvtx_k<<<MH*D_/1024, blk, 0, stream>>>(xh, (unsigned int*)hb);

    // mega: all 6 projections (N=6144), grid 3072 blocks (~12/CU)
    gemmH<0,1024><<<dim3(MH/128, 48), blk, 0, stream>>>(hb, wt_cat, bias_cat,
                                                        nullptr, cat1, nullptr);
    // p2: phi_init (from gelu(phi1))
    gemmH<1,1024><<<dim3(MH/128, 8), blk, 0, stream>>>(zphi1, wt_p2, bp2,
                                                       nullptr, zpin, nullptr);
    // scans
    scan1_k<<<256, blk, 0, stream>>>((unsigned int*)zgate,(unsigned int*)zmag,(unsigned int*)zomega,
                                     (const unsigned int*)zdt,(const unsigned int*)hb, sumPhi, sumGm);
    scan2_k<<<512, blk, 0, stream>>>(sumPhi, sumGm);
    scan3_k<<<256, blk, 0, stream>>>((const unsigned int*)zomega,(const unsigned int*)zgate,
                                     (const unsigned int*)zpin, sumPhi, sumRe, sumIm);
    scan2_k<<<512, blk, 0, stream>>>(sumRe, sumIm);
    scan5_k<<<256, blk, 0, stream>>>((const unsigned int*)zomega,(const unsigned int*)zgate,
                                     (const unsigned int*)zpin,(const unsigned int*)zmag,
                                     (const unsigned int*)zqoff,
                                     sumPhi, sumGm, sumRe, sumIm, (unsigned int*)ctx);

    // tail: LN + out MLP + residual
    ln_k<<<MH, blk, 0, stream>>>((unsigned int*)ctx, lng, lnb);
    gemmH<2,2048><<<dim3(MH/128, 8), blk, 0, stream>>>(ctx, wt_o1, bo1,
                                                       nullptr, a3, nullptr);
    gemmH<3,1024><<<dim3(MH/128, 8), blk, 0, stream>>>(a3, wt_o2, bo2,
                                                       xh, nullptr, outh);
  }
}